// Round 1
// baseline (256.665 us; speedup 1.0000x reference)
//
#include <hip/hip_runtime.h>
#include <math.h>

#define T_TOKENS 16384
#define HDIM     2048
#define NEXP     128
#define TOPK     8

#define BK    64                 // k per chunk (2 MFMA k-steps)
#define NCH   (HDIM / BK)        // 32 chunks
#define TM    64                 // tokens per block

#define F16_MIN_NORM    6.1035156e-05f
#define SPLIT_SCALE     4096.0f
#define INV_SPLIT_SCALE 2.44140625e-04f   // 2^-12

typedef __attribute__((ext_vector_type(8))) _Float16 f16x8;  // A/B frag: 4 VGPR
typedef __attribute__((ext_vector_type(4))) float    f32x4;  // C/D frag + loads

// x = hi + lo*2^-12 (f16 RNE each); residual <= 2^-24|x|. Numerics verified R3-R8.
__device__ __forceinline__ void f16split(float f, _Float16& hi, _Float16& lo) {
    _Float16 h = (_Float16)f;
    float back = (float)h;
    if (fabsf(f) < F16_MIN_NORM) { h = (_Float16)0.f; back = 0.f; }
    lo = (_Float16)((f - back) * SPLIT_SCALE);
    hi = h;
}

// ---- prep: split w AND repack into MFMA B-frag order (verified R5-R8, unchanged) ----
// packed[s]: ((kk*8 + nt)*64 + lane) * 8 f16; kk = global 32-k step, nt = expert/16.
__global__ __launch_bounds__(256) void pack_w(const float* __restrict__ w,
                                              unsigned short* __restrict__ wp1,
                                              unsigned short* __restrict__ wp2) {
    int p = blockIdx.x * 256 + threadIdx.x;       // 0 .. 64*8*64-1
    int lane = p & 63, nt = (p >> 6) & 7, kk = p >> 9;
    int col = lane & 15, quad = lane >> 4;
    const float* src = w + (size_t)(nt * 16 + col) * HDIM + kk * 32 + quad * 8;
    unsigned short h[8], l[8];
#pragma unroll
    for (int j = 0; j < 8; ++j) {
        _Float16 hh, ll;
        f16split(src[j], hh, ll);
        union { _Float16 x; unsigned short u; } ch, cl;
        ch.x = hh; cl.x = ll;
        h[j] = ch.u; l[j] = cl.u;
    }
    *(uint4*)(wp1 + (size_t)p * 8) = *(const uint4*)h;
    *(uint4*)(wp2 + (size_t)p * 8) = *(const uint4*)l;
}

// ---- fused gate v2: A direct-to-register, B double-buffered DMA, 1 barrier/chunk ----
// Block = 512 thr = 8 waves as 4 m-groups x 2 n-groups; tile 64 tokens x 128 experts.
// Wave (wm, wn): m-tile wm (16 tokens), experts [wn*64, +64) = 4 n-tiles.
// Grid 256 -> 1 block/CU (LDS 64 KB). Pipeline: iter ch issues A-loads + B-DMA for
// ch+1 BEFORE compute; the single end barrier's vmcnt(0) drain is then BW-paced.
__global__ __launch_bounds__(512, 2) void moe_gate(const float* __restrict__ x,
                                                   const unsigned short* __restrict__ wp1,
                                                   const unsigned short* __restrict__ wp2,
                                                   float* __restrict__ out_idx,
                                                   float* __restrict__ out_w) {
    // bsm[buf][plane]: [2kk][8nt][64 lane][8 f16] = 16 KB per plane -> 64 KB total
    __shared__ __align__(16) unsigned short bsm[2][2][8192];
    float* epil = (float*)bsm;                    // epilogue union [64][132] f32 = 33 KB

    const int tid  = threadIdx.x;
    const int lane = tid & 63;
    const int wv   = tid >> 6;        // 0..7
    const int wm   = wv >> 1;         // m-group 0..3
    const int wn   = wv & 1;          // n-group 0..1
    const int col  = lane & 15;       // A: token-in-tile, B: expert-in-tile, D: col
    const int quad = lane >> 4;       // A/B: k-seg, D: row group
    const long tok0 = (long)blockIdx.x * TM;

    // A-frag source: lane holds x[token = wm*16+col][k = ch*64 + kk*32 + quad*8 .. +8]
    // Wave access = 16 rows x 128 B full lines (coalesced). wn=0/1 duplicate -> L1/L2 hit.
    const float* xg = x + (tok0 + wm * 16 + col) * (long)HDIM + quad * 8;

    f32x4 acc[4], accc[4];            // [n-tile] main + cross, 32 VGPR
#pragma unroll
    for (int j = 0; j < 4; ++j) { acc[j] = (f32x4){0,0,0,0}; accc[j] = (f32x4){0,0,0,0}; }

    f32x4 xa0, xa1, xb0, xb1;         // prefetched 16 f32 (kk=0: xa, kk=1: xb)

    auto load_x = [&](int ch) {
        const float* p = xg + ch * BK;
        xa0 = *(const f32x4*)(p);
        xa1 = *(const f32x4*)(p + 4);
        xb0 = *(const f32x4*)(p + 32);
        xb1 = *(const f32x4*)(p + 36);
    };

    auto dma_b = [&](int ch, int buf) {
        const unsigned short* s1 = wp1 + (size_t)ch * 8192;
        const unsigned short* s2 = wp2 + (size_t)ch * 8192;
        unsigned short* d1 = &bsm[buf][0][0];
        unsigned short* d2 = &bsm[buf][1][0];
#pragma unroll
        for (int i = 0; i < 2; ++i) {
            const int off = (i * 512 + tid) * 8;   // f16 units, 16 B per thread
            __builtin_amdgcn_global_load_lds((const __attribute__((address_space(1))) void*)(s1 + off),
                                             (__attribute__((address_space(3))) void*)(d1 + off), 16, 0, 0);
            __builtin_amdgcn_global_load_lds((const __attribute__((address_space(1))) void*)(s2 + off),
                                             (__attribute__((address_space(3))) void*)(d2 + off), 16, 0, 0);
        }
    };

    // prologue: chunk 0 in flight, drained by the barrier
    load_x(0);
    dma_b(0, 0);
    __syncthreads();

    for (int ch = 0; ch < NCH; ++ch) {
        const int p = ch & 1;

        // in-register f16 split of this chunk's A (data arrived: prev barrier drained vmcnt)
        f16x8 af1[2], af2[2];
#pragma unroll
        for (int kk = 0; kk < 2; ++kk) {
            f32x4 v0 = kk ? xb0 : xa0;
            f32x4 v1 = kk ? xb1 : xa1;
#pragma unroll
            for (int j = 0; j < 8; ++j) {
                float f = (j < 4) ? v0[j] : v1[j - 4];
                _Float16 hh, ll;
                f16split(f, hh, ll);
                af1[kk][j] = hh;
                af2[kk][j] = ll;
            }
        }

        // issue next chunk's A loads + B DMA into the other buffer (overlaps compute)
        if (ch + 1 < NCH) { load_x(ch + 1); dma_b(ch + 1, p ^ 1); }

        const unsigned short* b1 = &bsm[p][0][0];
        const unsigned short* b2 = &bsm[p][1][0];
#pragma unroll
        for (int kk = 0; kk < 2; ++kk) {
#pragma unroll
            for (int j = 0; j < 4; ++j) {
                const int nt = wn * 4 + j;
                const int bo = ((kk * 8 + nt) * 64 + lane) * 8;   // lane-contiguous b128
                f16x8 bf1 = *(const f16x8*)(b1 + bo);
                f16x8 bf2 = *(const f16x8*)(b2 + bo);
                acc[j]  = __builtin_amdgcn_mfma_f32_16x16x32_f16(af1[kk], bf1, acc[j],  0, 0, 0);
                accc[j] = __builtin_amdgcn_mfma_f32_16x16x32_f16(af1[kk], bf2, accc[j], 0, 0, 0);
                accc[j] = __builtin_amdgcn_mfma_f32_16x16x32_f16(af2[kk], bf1, accc[j], 0, 0, 0);
            }
        }

        // one barrier: (a) all waves done reading bsm[p]; (b) drains next chunk's
        // A loads + DMA into bsm[p^1]. Stall here = memory pacing = the roofline.
        __syncthreads();
    }

    // ---- epilogue: logits -> LDS; D layout: token = wm*16+quad*4+r, expert = nt*16+col
#pragma unroll
    for (int j = 0; j < 4; ++j) {
        const int nt = wn * 4 + j;
#pragma unroll
        for (int r = 0; r < 4; ++r)
            epil[(wm * 16 + quad * 4 + r) * 132 + nt * 16 + col] =
                acc[j][r] + accc[j][r] * INV_SPLIT_SCALE;
    }
    __syncthreads();

    // ---- top-8 + renorm softmax: 8 tokens per wave (butterfly verified R1-R8) ----
    for (int i = 0; i < 8; ++i) {
        const int t = wv * 8 + i;
        float2 p = *(const float2*)(epil + t * 132 + 2 * lane);
        float v0 = p.x, v1 = p.y;
        const int i0 = 2 * lane, i1 = 2 * lane + 1;

        float topv[TOPK];
        int topi[TOPK];
#pragma unroll
        for (int s = 0; s < TOPK; ++s) {
            float mv = (v0 >= v1) ? v0 : v1;          // tie -> smaller index
            int   mi = (v0 >= v1) ? i0 : i1;
#pragma unroll
            for (int off = 32; off >= 1; off >>= 1) {
                float ov = __shfl_xor(mv, off);
                int   oi = __shfl_xor(mi, off);
                if (ov > mv || (ov == mv && oi < mi)) { mv = ov; mi = oi; }
            }
            topv[s] = mv; topi[s] = mi;
            if (i0 == mi) v0 = -INFINITY;
            if (i1 == mi) v1 = -INFINITY;
        }

        const float m = topv[0];
        float sum = 0.f;
#pragma unroll
        for (int s = 0; s < TOPK; ++s) sum += expf(topv[s] - m);
        const float inv = 1.f / sum;

        float myv = topv[0]; int myi = topi[0];
#pragma unroll
        for (int s = 1; s < TOPK; ++s)
            if (lane == s) { myv = topv[s]; myi = topi[s]; }

        if (lane < TOPK) {
            long tok = tok0 + t;
            out_idx[tok * TOPK + lane] = (float)myi;
            out_w[tok * TOPK + lane]   = expf(myv - m) * inv;
        }
    }
}

extern "C" void kernel_launch(void* const* d_in, const int* in_sizes, int n_in,
                              void* d_out, int out_size, void* d_ws, size_t ws_size,
                              hipStream_t stream) {
    const float* x = (const float*)d_in[0];   // [4,4096,2048] fp32
    const float* w = (const float*)d_in[1];   // [128,2048] fp32
    float* out = (float*)d_out;               // [T*8 idx][T*8 weights] flat fp32

    unsigned short* wp1 = (unsigned short*)d_ws;           // 512 KB packed hi
    unsigned short* wp2 = wp1 + (size_t)NEXP * HDIM;       // 512 KB packed lo

    pack_w<<<(64 * 8 * 64) / 256, 256, 0, stream>>>(w, wp1, wp2);
    moe_gate<<<T_TOKENS / TM, 512, 0, stream>>>(x, wp1, wp2, out, out + (size_t)T_TOKENS * TOPK);
}